// Round 10
// baseline (359.016 us; speedup 1.0000x reference)
//
#include <hip/hip_runtime.h>

// Morphological skeleton, 16 x 1024 x 1024 f32.
// skel = sum_{k=0..20} ( e_k - dilate3x3(e_{k+1}) ),  e_0 = x, e_{k+1} = erode3x3(e_k)
// (reduce_window SAME semantics: windows clamp at image borders).
//
// Register-resident vertical pipeline, zero LDS tile. 3 dispatches x G=7 fused
// erosion stages. One wave (64 lanes x float4) owns a 256-col band and sweeps
// RCH+16 rows in (RCH+16)/2 two-row steps (R9 structure).
//
// Round-14 change vs round 13 (327 us): attack the CONTROL/bookkeeping stream.
// Ledger: time responds only to DS-latency removal (R5 -10%), on-chain VALU
// adds (R2 +38%), VGPR occupancy collapse (R6 +22%); NOT to wave count, ILP,
// off-chain VALU cuts, or chain-depth halving (R9: 0%). VALUBusy(45%) x 97.6us
// = 44us of issue ~= 2x the source-level datapath ops: the other half is
// guards (6 guarded accesses/step: SALU cmp+branch+exec save/restore), 64-bit
// address math, and 50%-of-steps warm-up at RCH=32. Cuts:
//  (a) RCH 32->64: warm-up 16/48 -> 16/80 of steps (-17% steps per row).
//  (b) phase-split: WARM (4 steps, erode-only fill: no dilate/acc/stores) ->
//      GUARD (4 transition steps, runtime guards) -> STEADY (28 steps, ALL
//      loads/stores unconditional) -> GUARD drain (4). Edge chunks (y0 = 0 /
//      960, 12.5% of waves) use the all-GUARD generic loop.
//
// Phase-range desk-proofs (interior, t0 = y0-8, steps t += 2):
//  - WARM t = y0-8..y0-2: no row >= y0 is stored/seeded; erode-only is safe
//    because dilate outputs of these steps land in never-emitted rows; acc
//    slots touched here are re-assigned/seeded before any emitted row's use.
//  - GUARD pre t = y0..y0+6: seeds rows y0..y0+7; e-write only row y0 (er1 at
//    t=y0+6); no emits (t < y0+8).
//  - STEADY t = y0+8..y0+62: emits rows t-8,t-7 in [y0, y0+55]; e-writes
//    er0=t-7 in [y0+1,y0+55], er1=t-6 in [y0+2,y0+56]; seeds rows t,t+1 in
//    [y0+8, y0+63]; prefetch nr <= y0+65 <= 993 < H. All statically in-range.
//  - GUARD drain t = y0+64..y0+70: emits y0+56..y0+63; e-writes er0 odd rows
//    y0+57..63, er1 even y0+58..62 (y0+64 guarded off); seeds guarded off.
//    Full coverage: emit rows y0..y0+63; e-rows y0 (pre) + all others ✓.
//  - seed->consume ordering: row r seeded at end of step t=r (or r-1), first
//    accumulated by stage 0 at step r+2 (rows t-2,t-1), emitted at r+8 after
//    stage-6's same-step write. Shift acc[j]=acc[j+2] runs in every non-WARM
//    step; WARM skips it (nothing seeded yet; FIRST's earliest kept row y0-2
//    is assigned at t=y0, within GUARD).
//  - interior iff 32 <= y0 <= H-RCH-32 = 928: warm-up rows >= y0-8 >= 24 in-
//    image; prefetch max row y0+73 <= 1001 < H.
//
// Config carried: 4-wave WGs, EDGE folding, DPP wave-shifts, LE/RE band
// templating, 2-row steps with shared stage buffers, acc-ring seeding.
//
// Other invariants unchanged from R13 (two-row algebra, DPP 0-fill halo
// contamination absorbed by 8-col shrink, disjoint band write ownership
// {[0,248),[248,488),[488,728),[728,968),[968,1024)}).

static constexpr int W = 1024, H = 1024, NIMG = 16;
static constexpr int RCH = 64;           // output rows per wave
static constexpr int WPB = 4;            // waves per workgroup
static constexpr float BIG = 3.0e38f;

__device__ __forceinline__ float min3f(float a, float b, float c) { return fminf(fminf(a, b), c); }
__device__ __forceinline__ float max3f(float a, float b, float c) { return fmaxf(fmaxf(a, b), c); }

// DPP whole-wave shifts (gfx9/CDNA-only modes; VALU pipe, no DS).
// wave_shr:1 = 0x138 -> lane i reads lane i-1; lane 0 = 0.
// wave_shl:1 = 0x130 -> lane i reads lane i+1; lane 63 = 0.
__device__ __forceinline__ float dpp_left(float v) {
    return __int_as_float(__builtin_amdgcn_mov_dpp(__float_as_int(v), 0x138, 0xF, 0xF, true));
}
__device__ __forceinline__ float dpp_right(float v) {
    return __int_as_float(__builtin_amdgcn_mov_dpp(__float_as_int(v), 0x130, 0xF, 0xF, true));
}

// MODE: 0 = WARM   (pipeline fill: erode+rotate only; no dilate/acc/stores/seeds/shift)
//       1 = GUARD  (all stores/seeds under runtime range checks)
//       2 = STEADY (all loads/stores unconditional; interior chunks only)
template<bool FIRST, bool WRITE_E, bool EDGE, bool LE, bool RE, int MODE>
__device__ __forceinline__
void pipe_step2(int t, int y0, int gx,
                bool leftEdge, bool rightEdge, bool lane_ok,
                const float* __restrict__ in, float* __restrict__ eo,
                float* __restrict__ sk,
                float4 (&OB)[7], float4 (&MB)[7], float4& OD, float4& MD,
                float4 (&acc)[8], float4 (&pf)[2])
{
    // consume input rows t, t+1 (OOB rows +BIG: erode identity)
    float4 cur0, cur1;
    if (!EDGE || (unsigned)t < (unsigned)H)       cur0 = pf[0];
    else                                          cur0 = make_float4(BIG, BIG, BIG, BIG);
    if (!EDGE || (unsigned)(t + 1) < (unsigned)H) cur1 = pf[1];
    else                                          cur1 = make_float4(BIG, BIG, BIG, BIG);
    // prefetch rows t+2, t+3 (consumed next step); unconditional except GUARD
    {
        const int n0 = t + 2, n1 = t + 3;
        if (MODE != 1 || ((!EDGE || (unsigned)n0 < (unsigned)H) && n0 <= y0 + RCH + 7))
            pf[0] = *(const float4*)&in[(size_t)n0 * W + gx];
        if (MODE != 1 || ((!EDGE || (unsigned)n1 < (unsigned)H) && n1 <= y0 + RCH + 7))
            pf[1] = *(const float4*)&in[(size_t)n1 * W + gx];
    }

#pragma unroll
    for (int s = 0; s < 7; ++s) {
        const float4 fOld = OB[s];   // f_s(t-s-2)
        const float4 fMid = MB[s];   // f_s(t-s-1)

        // ---- erode both rows: en0 = f_{s+1}(t-s-1), en1 = f_{s+1}(t-s) ----
        float4 vm0, vm1;
        vm0.x = min3f(fOld.x, fMid.x, cur0.x);
        vm0.y = min3f(fOld.y, fMid.y, cur0.y);
        vm0.z = min3f(fOld.z, fMid.z, cur0.z);
        vm0.w = min3f(fOld.w, fMid.w, cur0.w);
        vm1.x = min3f(fMid.x, cur0.x, cur1.x);
        vm1.y = min3f(fMid.y, cur0.y, cur1.y);
        vm1.z = min3f(fMid.z, cur0.z, cur1.z);
        vm1.w = min3f(fMid.w, cur0.w, cur1.w);
        float l0 = dpp_left(vm0.w), r0 = dpp_right(vm0.x);
        float l1 = dpp_left(vm1.w), r1 = dpp_right(vm1.x);
        if (LE && leftEdge)  { l0 = BIG; l1 = BIG; }
        if (RE && rightEdge) { r0 = BIG; r1 = BIG; }
        float4 en0, en1;
        en0.x = min3f(l0,    vm0.x, vm0.y);
        en0.y = min3f(vm0.x, vm0.y, vm0.z);
        en0.z = min3f(vm0.y, vm0.z, vm0.w);
        en0.w = min3f(vm0.z, vm0.w, r0);
        en1.x = min3f(l1,    vm1.x, vm1.y);
        en1.y = min3f(vm1.x, vm1.y, vm1.z);
        en1.z = min3f(vm1.y, vm1.z, vm1.w);
        en1.w = min3f(vm1.z, vm1.w, r1);

        if (MODE != 0) {
            // ---- dilate of f_{s+1}: centers t-s-2 (dn0), t-s-1 (dn1) ----
            float4 gOld, gMid;   // f_{s+1}(t-s-3), f_{s+1}(t-s-2): pre-update
            if (s < 6) { gOld = OB[s + 1]; gMid = MB[s + 1]; }
            else       { gOld = OD;        gMid = MD;        }
            float4 vx0, vx1;
            if (!EDGE) {
                vx0.x = max3f(gOld.x, gMid.x, en0.x);
                vx0.y = max3f(gOld.y, gMid.y, en0.y);
                vx0.z = max3f(gOld.z, gMid.z, en0.z);
                vx0.w = max3f(gOld.w, gMid.w, en0.w);
                vx1.x = max3f(gMid.x, en0.x, en1.x);
                vx1.y = max3f(gMid.y, en0.y, en1.y);
                vx1.z = max3f(gMid.z, en0.z, en1.z);
                vx1.w = max3f(gMid.w, en0.w, en1.w);
            } else {
                const bool topOK0 = (t - s - 3) >= 0, botOK0 = (t - s - 1) < H;
                const bool topOK1 = (t - s - 2) >= 0, botOK1 = (t - s) < H;
                vx0.x = max3f(topOK0 ? gOld.x : -BIG, gMid.x, botOK0 ? en0.x : -BIG);
                vx0.y = max3f(topOK0 ? gOld.y : -BIG, gMid.y, botOK0 ? en0.y : -BIG);
                vx0.z = max3f(topOK0 ? gOld.z : -BIG, gMid.z, botOK0 ? en0.z : -BIG);
                vx0.w = max3f(topOK0 ? gOld.w : -BIG, gMid.w, botOK0 ? en0.w : -BIG);
                vx1.x = max3f(topOK1 ? gMid.x : -BIG, en0.x, botOK1 ? en1.x : -BIG);
                vx1.y = max3f(topOK1 ? gMid.y : -BIG, en0.y, botOK1 ? en1.y : -BIG);
                vx1.z = max3f(topOK1 ? gMid.z : -BIG, en0.z, botOK1 ? en1.z : -BIG);
                vx1.w = max3f(topOK1 ? gMid.w : -BIG, en0.w, botOK1 ? en1.w : -BIG);
            }
            float dl0 = dpp_left(vx0.w), dr0 = dpp_right(vx0.x);
            float dl1 = dpp_left(vx1.w), dr1 = dpp_right(vx1.x);
            if (LE && leftEdge)  { dl0 = -BIG; dl1 = -BIG; }
            if (RE && rightEdge) { dr0 = -BIG; dr1 = -BIG; }
            float4 dn0, dn1;
            dn0.x = max3f(dl0,   vx0.x, vx0.y);
            dn0.y = max3f(vx0.x, vx0.y, vx0.z);
            dn0.z = max3f(vx0.y, vx0.z, vx0.w);
            dn0.w = max3f(vx0.z, vx0.w, dr0);
            dn1.x = max3f(dl1,   vx1.x, vx1.y);
            dn1.y = max3f(vx1.x, vx1.y, vx1.z);
            dn1.z = max3f(vx1.y, vx1.z, vx1.w);
            dn1.w = max3f(vx1.z, vx1.w, dr1);

            // terms: row t-s-2 -> slot 6-s; row t-s-1 -> slot 7-s
            if (FIRST && s == 0) {
                acc[6].x = fOld.x - dn0.x;  acc[6].y = fOld.y - dn0.y;
                acc[6].z = fOld.z - dn0.z;  acc[6].w = fOld.w - dn0.w;
                acc[7].x = fMid.x - dn1.x;  acc[7].y = fMid.y - dn1.y;
                acc[7].z = fMid.z - dn1.z;  acc[7].w = fMid.w - dn1.w;
            } else {
                acc[6 - s].x += fOld.x - dn0.x;  acc[6 - s].y += fOld.y - dn0.y;
                acc[6 - s].z += fOld.z - dn0.z;  acc[6 - s].w += fOld.w - dn0.w;
                acc[7 - s].x += fMid.x - dn1.x;  acc[7 - s].y += fMid.y - dn1.y;
                acc[7 - s].z += fMid.z - dn1.z;  acc[7 - s].w += fMid.w - dn1.w;
            }
        }

        // rotate: buffers take the two incoming rows
        OB[s] = cur0;
        MB[s] = cur1;

        if (s == 6) {
            if (WRITE_E && MODE != 0) {
                const int er0 = t - 7, er1 = t - 6;   // f_7 rows
                if (MODE == 2) {
                    if (lane_ok) {
                        *(float4*)&eo[(size_t)er0 * W + gx] = en0;
                        *(float4*)&eo[(size_t)er1 * W + gx] = en1;
                    }
                } else {
                    if (er0 >= y0 && er0 < y0 + RCH && lane_ok)
                        *(float4*)&eo[(size_t)er0 * W + gx] = en0;
                    if (er1 >= y0 && er1 < y0 + RCH && lane_ok)
                        *(float4*)&eo[(size_t)er1 * W + gx] = en1;
                }
            }
            OD = en0;
            MD = en1;
        }
        cur0 = en0;
        cur1 = en1;
    }

    if (MODE != 0) {
        // ---- emit completed rows t-8, t-7 (slots 0,1) ----
        if (MODE == 2) {
            if (lane_ok) {
                *(float4*)&sk[(size_t)(t - 8) * W + gx] = acc[0];
                *(float4*)&sk[(size_t)(t - 7) * W + gx] = acc[1];
            }
        } else {
            if (t >= y0 + 8 && lane_ok) {
                *(float4*)&sk[(size_t)(t - 8) * W + gx] = acc[0];
                *(float4*)&sk[(size_t)(t - 7) * W + gx] = acc[1];
            }
        }
        // one shift per 2-row step
#pragma unroll
        for (int j = 0; j < 6; ++j) acc[j] = acc[j + 2];
        // seed slots 6,7 (rows t, t+1) with OLD skel; stage-0 += at t+2
        if (!FIRST) {
            if (MODE == 2) {
                acc[6] = *(const float4*)&sk[(size_t)t * W + gx];
                acc[7] = *(const float4*)&sk[(size_t)(t + 1) * W + gx];
            } else {
                if (t >= y0 && t < y0 + RCH)
                    acc[6] = *(const float4*)&sk[(size_t)t * W + gx];
                if (t + 1 >= y0 && t + 1 < y0 + RCH)
                    acc[7] = *(const float4*)&sk[(size_t)(t + 1) * W + gx];
            }
        }
    }
}

template<bool FIRST, bool WRITE_E, bool LE, bool RE>
__device__ __forceinline__
void sweep_int(int y0, int gx, bool leftEdge, bool rightEdge, bool lane_ok,
               const float* __restrict__ in, float* __restrict__ eo,
               float* __restrict__ sk)
{
    float4 OB[7], MB[7], OD, MD, acc[8], pf[2];
    const float4 big4 = make_float4(BIG, BIG, BIG, BIG);
    const float4 z4   = make_float4(0.f, 0.f, 0.f, 0.f);
#pragma unroll
    for (int s = 0; s < 7; ++s) { OB[s] = big4; MB[s] = big4; }
    OD = big4; MD = big4;
#pragma unroll
    for (int j = 0; j < 8; ++j) acc[j] = z4;
    // interior: rows y0-8, y0-7 always in-image
    pf[0] = *(const float4*)&in[(size_t)(y0 - 8) * W + gx];
    pf[1] = *(const float4*)&in[(size_t)(y0 - 7) * W + gx];

    int t = y0 - 8;
#pragma unroll
    for (int i = 0; i < 4; ++i, t += 2)     // WARM: t = y0-8 .. y0-2
        pipe_step2<FIRST, WRITE_E, false, LE, RE, 0>(t, y0, gx, leftEdge, rightEdge, lane_ok,
                                                     in, eo, sk, OB, MB, OD, MD, acc, pf);
#pragma unroll 1
    for (int i = 0; i < 4; ++i, t += 2)     // GUARD pre: t = y0 .. y0+6
        pipe_step2<FIRST, WRITE_E, false, LE, RE, 1>(t, y0, gx, leftEdge, rightEdge, lane_ok,
                                                     in, eo, sk, OB, MB, OD, MD, acc, pf);
#pragma unroll 1
    for (int i = 0; i < 28; ++i, t += 2)    // STEADY: t = y0+8 .. y0+62
        pipe_step2<FIRST, WRITE_E, false, LE, RE, 2>(t, y0, gx, leftEdge, rightEdge, lane_ok,
                                                     in, eo, sk, OB, MB, OD, MD, acc, pf);
#pragma unroll 1
    for (int i = 0; i < 4; ++i, t += 2)     // GUARD drain: t = y0+64 .. y0+70
        pipe_step2<FIRST, WRITE_E, false, LE, RE, 1>(t, y0, gx, leftEdge, rightEdge, lane_ok,
                                                     in, eo, sk, OB, MB, OD, MD, acc, pf);
}

template<bool FIRST, bool WRITE_E, bool LE, bool RE>
__device__ __forceinline__
void sweep_edge(int y0, int gx, bool leftEdge, bool rightEdge, bool lane_ok,
                const float* __restrict__ in, float* __restrict__ eo,
                float* __restrict__ sk)
{
    float4 OB[7], MB[7], OD, MD, acc[8], pf[2];
    const float4 big4 = make_float4(BIG, BIG, BIG, BIG);
    const float4 z4   = make_float4(0.f, 0.f, 0.f, 0.f);
#pragma unroll
    for (int s = 0; s < 7; ++s) { OB[s] = big4; MB[s] = big4; }
    OD = big4; MD = big4;
#pragma unroll
    for (int j = 0; j < 8; ++j) acc[j] = z4;
    pf[0] = big4; pf[1] = big4;
    {
        const int r0 = y0 - 8, r1 = y0 - 7;
        if (r0 >= 0) pf[0] = *(const float4*)&in[(size_t)r0 * W + gx];
        if (r1 >= 0) pf[1] = *(const float4*)&in[(size_t)r1 * W + gx];
    }

    int t = y0 - 8;
#pragma unroll 1
    for (int i = 0; i < (RCH + 16) / 2; ++i, t += 2)
        pipe_step2<FIRST, WRITE_E, true, LE, RE, 1>(t, y0, gx, leftEdge, rightEdge, lane_ok,
                                                    in, eo, sk, OB, MB, OD, MD, acc, pf);
}

template<bool FIRST, bool WRITE_E>
__global__ __launch_bounds__(WPB * 64)
void skel_pipe(const float* __restrict__ ein, float* __restrict__ eout,
               float* __restrict__ skel)
{
    const int lane = threadIdx.x;          // 64 lanes; threadIdx.y selects the wave
    const int bx = blockIdx.x;             // band 0..4
    const int y0 = (blockIdx.y * WPB + (int)threadIdx.y) * RCH;  // private row chunk
    const int img = blockIdx.z;
    const int x0 = (bx == 4) ? 768 : bx * 240;   // last band starts at 1024-256
    const int gx = x0 + 4 * lane;                // gx max = 768 + 252 = 1020

    const size_t base = (size_t)img * (size_t)(W * H);
    const float* __restrict__ in = ein + base;
    float* __restrict__ eo = eout + base;
    float* __restrict__ sk = skel + base;

    const bool leftEdge  = (gx == 0);
    const bool rightEdge = (gx + 4 == W);
    // disjoint write ownership (bands overlap in compute, never in writes)
    const int own_lo = (bx == 0) ? 0 : ((bx == 4) ? 968 : x0 + 8);
    const int own_hi = (bx == 4) ? W : x0 + 248;
    const bool lane_ok = (gx >= own_lo) && (gx < own_hi);

    // interior iff 32 <= y0 <= H-RCH-32 (= 928): full warm-up cone in-image
    const bool interior = (y0 >= 32 && y0 <= H - RCH - 32);

    if (bx == 0) {
        if (interior) sweep_int <FIRST, WRITE_E, true,  false>(y0, gx, leftEdge, rightEdge, lane_ok, in, eo, sk);
        else          sweep_edge<FIRST, WRITE_E, true,  false>(y0, gx, leftEdge, rightEdge, lane_ok, in, eo, sk);
    } else if (bx == 4) {
        if (interior) sweep_int <FIRST, WRITE_E, false, true >(y0, gx, leftEdge, rightEdge, lane_ok, in, eo, sk);
        else          sweep_edge<FIRST, WRITE_E, false, true >(y0, gx, leftEdge, rightEdge, lane_ok, in, eo, sk);
    } else {
        if (interior) sweep_int <FIRST, WRITE_E, false, false>(y0, gx, leftEdge, rightEdge, lane_ok, in, eo, sk);
        else          sweep_edge<FIRST, WRITE_E, false, false>(y0, gx, leftEdge, rightEdge, lane_ok, in, eo, sk);
    }
}

extern "C" void kernel_launch(void* const* d_in, const int* in_sizes, int n_in,
                              void* d_out, int out_size, void* d_ws, size_t ws_size,
                              hipStream_t stream)
{
    const float* x = (const float*)d_in[0];
    float* skel = (float*)d_out;
    const size_t n = (size_t)NIMG * W * H;

    float* e0 = (float*)d_ws;
    float* e1 = e0 + n;

    dim3 grid(5, H / (RCH * WPB), NIMG);
    dim3 block(64, WPB);

    // steps 0-6: x -> e0 ; 7-13: e0 -> e1 ; 14-20: e1 -> (none)
    skel_pipe<true,  true ><<<grid, block, 0, stream>>>(x,  e0, skel);
    skel_pipe<false, true ><<<grid, block, 0, stream>>>(e0, e1, skel);
    skel_pipe<false, false><<<grid, block, 0, stream>>>(e1, e0, skel);
}

// Round 11
// 302.943 us; speedup vs baseline: 1.1851x; 1.1851x over previous
//
#include <hip/hip_runtime.h>

// Morphological skeleton, 16 x 1024 x 1024 f32.
// skel = sum_{k=0..20} ( e_k - dilate3x3(e_{k+1}) ),  e_0 = x, e_{k+1} = erode3x3(e_k)
// (reduce_window SAME semantics: windows clamp at image borders).
//
// Register-resident vertical pipeline, zero LDS tile. 3 dispatches x G=7 fused
// erosion stages. One wave (64 lanes x FLOAT2) owns a 128-col band and sweeps
// RCH+16 rows in (RCH+16)/2 two-row steps.
//
// Round-15 change vs rounds 9/10 (327/359 us): wave-count axis. Ledger: busy%
// tracks instruction count exactly (R7 -15%->44, R10 -20%->35, R1 +20%->49)
// while wall time is INVARIANT ~96-101 us/dispatch for every config with
// >=1280 waves and VGPR<=128 => per-wave stall-dominated, covered only by
// resident waves; max ever launched was 2560 = 2.5/SIMD. R1's "2x waves ->
// flat" added only warm-up waste and duty rose by exactly that fraction: the
// fill mechanism works. This round: SAME total work split over 1.8x waves:
//  - float2 lanes -> 128-col bands -> 9 bands, owned widths 120/112x7/120;
//  - grid 9 x 16 x 16, 2-wave WGs: 4608 waves (4.5/SIMD), 2304 WGs = 9/CU
//    exactly (no integer-imbalance tail);
//  - per-wave state halves: VGPR ~80-100 (4/SIMD allowed, far from 128 cliff);
//  - carries: R9 2-row steps, DPP shifts, R10 WARM/GUARD/STEADY phase split
//    re-derived for RCH=32, LE/RE/EDGE templating, acc-ring skel seeding.
//
// Band geometry (desk-verified disjoint cover):
//  x0 = (b==0) ? 0 : (b==8) ? 896 : 112*b;  gx = x0 + 2*lane (covers gx,gx+1)
//  owned: b0 [0,120), b1..b7 [112b+8, 112(b+1)+8), b8 [904,1024).
//  120 + 7*112 + 120 = 1024; boundaries even -> ownership respects lane pairs.
//  leftEdge only b0 lane 0; rightEdge only b8 lane 63. 8-col halo each side:
//  DPP garbage propagates 1 col/stage; 7 erodes + 1 dilate = 8 cols absorbed.
//
// Phase-range desk-proofs (interior, RCH=32, t0 = y0-8, steps t += 2):
//  - WARM x4   t = y0-8..y0-2 : erode+rotate only; prefetch rows <= y0+1, all
//    in-image (interior y0 >= 32); no acc/stores/seeds/shift. Rows touched by
//    skipped stage-0 assigns (< y0-2) are never emitted.
//  - GUARD x4  t = y0..y0+6   : runtime guards; seeds rows y0..y0+7; e-write
//    only row y0; no emits (t < y0+8).
//  - STEADY x12 t = y0+8..y0+30: ALL unconditional. emits t-8,t-7 in
//    [y0,y0+23]; e-writes t-7,t-6 in [y0+1,y0+24]; seeds t,t+1 in [y0+8,
//    y0+31]; prefetch rows <= y0+33 <= 993 < H. All statically in-range.
//  - GUARD x4  t = y0+32..y0+38: emits y0+24..y0+31; seeds guarded off;
//    prefetch guard n <= y0+39. Coverage: emits y0..y0+31, e-rows y0..y0+32?
//    e-rows y0+1..y0+32 from steady+drain er0/er1 ranges + y0 from GUARD-pre:
//    full [y0, y0+31] for emit and e both (er1 at t=y0+38 is y0+32, guarded
//    off by er1 < y0+RCH).
//  - interior iff 32 <= y0 <= H-RCH-32 = 960: warm cone rows >= y0-8 >= 24.
//  - seed->consume: row r seeded at step t=r (slot 6) or t=r-1 (slot 7),
//    stage-0 += at step r+2, emitted at r+8 after stage-6's same-step write;
//    shift acc[j]=acc[j+2] every non-WARM step keeps slot j = row t-8+j.
//
// Other invariants from R9/R10 unchanged (two-row stage algebra, OOB +BIG
// rows harmless in min chains / masked in EDGE dilates, disjoint band write
// ownership => skel RMW never races).

static constexpr int W = 1024, H = 1024, NIMG = 16;
static constexpr int RCH = 32;           // output rows per wave
static constexpr int WPB = 2;            // waves per workgroup
static constexpr int NBAND = 9;          // 128-col bands
static constexpr float BIG = 3.0e38f;

__device__ __forceinline__ float min3f(float a, float b, float c) { return fminf(fminf(a, b), c); }
__device__ __forceinline__ float max3f(float a, float b, float c) { return fmaxf(fmaxf(a, b), c); }

// DPP whole-wave shifts (gfx9/CDNA-only modes; VALU pipe, no DS).
// wave_shr:1 = 0x138 -> lane i reads lane i-1; lane 0 = 0.
// wave_shl:1 = 0x130 -> lane i reads lane i+1; lane 63 = 0.
__device__ __forceinline__ float dpp_left(float v) {
    return __int_as_float(__builtin_amdgcn_mov_dpp(__float_as_int(v), 0x138, 0xF, 0xF, true));
}
__device__ __forceinline__ float dpp_right(float v) {
    return __int_as_float(__builtin_amdgcn_mov_dpp(__float_as_int(v), 0x130, 0xF, 0xF, true));
}

// MODE: 0 = WARM   (pipeline fill: erode+rotate only)
//       1 = GUARD  (all stores/seeds under runtime range checks)
//       2 = STEADY (all loads/stores unconditional; interior chunks only)
template<bool FIRST, bool WRITE_E, bool EDGE, bool LE, bool RE, int MODE>
__device__ __forceinline__
void pipe_step2(int t, int y0, int gx,
                bool leftEdge, bool rightEdge, bool lane_ok,
                const float* __restrict__ in, float* __restrict__ eo,
                float* __restrict__ sk,
                float2 (&OB)[7], float2 (&MB)[7], float2& OD, float2& MD,
                float2 (&acc)[8], float2 (&pf)[2])
{
    // consume input rows t, t+1 (OOB rows +BIG: erode identity)
    float2 cur0, cur1;
    if (!EDGE || (unsigned)t < (unsigned)H)       cur0 = pf[0];
    else                                          cur0 = make_float2(BIG, BIG);
    if (!EDGE || (unsigned)(t + 1) < (unsigned)H) cur1 = pf[1];
    else                                          cur1 = make_float2(BIG, BIG);
    // prefetch rows t+2, t+3 (consumed next step); unconditional except GUARD
    {
        const int n0 = t + 2, n1 = t + 3;
        if (MODE != 1 || ((!EDGE || (unsigned)n0 < (unsigned)H) && n0 <= y0 + RCH + 7))
            pf[0] = *(const float2*)&in[(size_t)n0 * W + gx];
        if (MODE != 1 || ((!EDGE || (unsigned)n1 < (unsigned)H) && n1 <= y0 + RCH + 7))
            pf[1] = *(const float2*)&in[(size_t)n1 * W + gx];
    }

#pragma unroll
    for (int s = 0; s < 7; ++s) {
        const float2 fOld = OB[s];   // f_s(t-s-2)
        const float2 fMid = MB[s];   // f_s(t-s-1)

        // ---- erode both rows: en0 = f_{s+1}(t-s-1), en1 = f_{s+1}(t-s) ----
        float2 vm0, vm1;
        vm0.x = min3f(fOld.x, fMid.x, cur0.x);
        vm0.y = min3f(fOld.y, fMid.y, cur0.y);
        vm1.x = min3f(fMid.x, cur0.x, cur1.x);
        vm1.y = min3f(fMid.y, cur0.y, cur1.y);
        float l0 = dpp_left(vm0.y), r0 = dpp_right(vm0.x);
        float l1 = dpp_left(vm1.y), r1 = dpp_right(vm1.x);
        if (LE && leftEdge)  { l0 = BIG; l1 = BIG; }
        if (RE && rightEdge) { r0 = BIG; r1 = BIG; }
        float2 en0, en1;
        en0.x = min3f(l0,    vm0.x, vm0.y);
        en0.y = min3f(vm0.x, vm0.y, r0);
        en1.x = min3f(l1,    vm1.x, vm1.y);
        en1.y = min3f(vm1.x, vm1.y, r1);

        if (MODE != 0) {
            // ---- dilate of f_{s+1}: centers t-s-2 (dn0), t-s-1 (dn1) ----
            float2 gOld, gMid;   // f_{s+1}(t-s-3), f_{s+1}(t-s-2): pre-update
            if (s < 6) { gOld = OB[s + 1]; gMid = MB[s + 1]; }
            else       { gOld = OD;        gMid = MD;        }
            float2 vx0, vx1;
            if (!EDGE) {
                vx0.x = max3f(gOld.x, gMid.x, en0.x);
                vx0.y = max3f(gOld.y, gMid.y, en0.y);
                vx1.x = max3f(gMid.x, en0.x, en1.x);
                vx1.y = max3f(gMid.y, en0.y, en1.y);
            } else {
                const bool topOK0 = (t - s - 3) >= 0, botOK0 = (t - s - 1) < H;
                const bool topOK1 = (t - s - 2) >= 0, botOK1 = (t - s) < H;
                vx0.x = max3f(topOK0 ? gOld.x : -BIG, gMid.x, botOK0 ? en0.x : -BIG);
                vx0.y = max3f(topOK0 ? gOld.y : -BIG, gMid.y, botOK0 ? en0.y : -BIG);
                vx1.x = max3f(topOK1 ? gMid.x : -BIG, en0.x, botOK1 ? en1.x : -BIG);
                vx1.y = max3f(topOK1 ? gMid.y : -BIG, en0.y, botOK1 ? en1.y : -BIG);
            }
            float dl0 = dpp_left(vx0.y), dr0 = dpp_right(vx0.x);
            float dl1 = dpp_left(vx1.y), dr1 = dpp_right(vx1.x);
            if (LE && leftEdge)  { dl0 = -BIG; dl1 = -BIG; }
            if (RE && rightEdge) { dr0 = -BIG; dr1 = -BIG; }
            float2 dn0, dn1;
            dn0.x = max3f(dl0,   vx0.x, vx0.y);
            dn0.y = max3f(vx0.x, vx0.y, dr0);
            dn1.x = max3f(dl1,   vx1.x, vx1.y);
            dn1.y = max3f(vx1.x, vx1.y, dr1);

            // terms: row t-s-2 -> slot 6-s; row t-s-1 -> slot 7-s
            if (FIRST && s == 0) {
                acc[6].x = fOld.x - dn0.x;  acc[6].y = fOld.y - dn0.y;
                acc[7].x = fMid.x - dn1.x;  acc[7].y = fMid.y - dn1.y;
            } else {
                acc[6 - s].x += fOld.x - dn0.x;  acc[6 - s].y += fOld.y - dn0.y;
                acc[7 - s].x += fMid.x - dn1.x;  acc[7 - s].y += fMid.y - dn1.y;
            }
        }

        // rotate: buffers take the two incoming rows
        OB[s] = cur0;
        MB[s] = cur1;

        if (s == 6) {
            if (WRITE_E && MODE != 0) {
                const int er0 = t - 7, er1 = t - 6;   // f_7 rows
                if (MODE == 2) {
                    if (lane_ok) {
                        *(float2*)&eo[(size_t)er0 * W + gx] = en0;
                        *(float2*)&eo[(size_t)er1 * W + gx] = en1;
                    }
                } else {
                    if (er0 >= y0 && er0 < y0 + RCH && lane_ok)
                        *(float2*)&eo[(size_t)er0 * W + gx] = en0;
                    if (er1 >= y0 && er1 < y0 + RCH && lane_ok)
                        *(float2*)&eo[(size_t)er1 * W + gx] = en1;
                }
            }
            OD = en0;
            MD = en1;
        }
        cur0 = en0;
        cur1 = en1;
    }

    if (MODE != 0) {
        // ---- emit completed rows t-8, t-7 (slots 0,1) ----
        if (MODE == 2) {
            if (lane_ok) {
                *(float2*)&sk[(size_t)(t - 8) * W + gx] = acc[0];
                *(float2*)&sk[(size_t)(t - 7) * W + gx] = acc[1];
            }
        } else {
            if (t >= y0 + 8 && lane_ok) {
                *(float2*)&sk[(size_t)(t - 8) * W + gx] = acc[0];
                *(float2*)&sk[(size_t)(t - 7) * W + gx] = acc[1];
            }
        }
        // one shift per 2-row step
#pragma unroll
        for (int j = 0; j < 6; ++j) acc[j] = acc[j + 2];
        // seed slots 6,7 (rows t, t+1) with OLD skel; stage-0 += at t+2
        if (!FIRST) {
            if (MODE == 2) {
                acc[6] = *(const float2*)&sk[(size_t)t * W + gx];
                acc[7] = *(const float2*)&sk[(size_t)(t + 1) * W + gx];
            } else {
                if (t >= y0 && t < y0 + RCH)
                    acc[6] = *(const float2*)&sk[(size_t)t * W + gx];
                if (t + 1 >= y0 && t + 1 < y0 + RCH)
                    acc[7] = *(const float2*)&sk[(size_t)(t + 1) * W + gx];
            }
        }
    }
}

template<bool FIRST, bool WRITE_E, bool LE, bool RE>
__device__ __forceinline__
void sweep_int(int y0, int gx, bool leftEdge, bool rightEdge, bool lane_ok,
               const float* __restrict__ in, float* __restrict__ eo,
               float* __restrict__ sk)
{
    float2 OB[7], MB[7], OD, MD, acc[8], pf[2];
    const float2 big2 = make_float2(BIG, BIG);
    const float2 z2   = make_float2(0.f, 0.f);
#pragma unroll
    for (int s = 0; s < 7; ++s) { OB[s] = big2; MB[s] = big2; }
    OD = big2; MD = big2;
#pragma unroll
    for (int j = 0; j < 8; ++j) acc[j] = z2;
    // interior: rows y0-8, y0-7 always in-image
    pf[0] = *(const float2*)&in[(size_t)(y0 - 8) * W + gx];
    pf[1] = *(const float2*)&in[(size_t)(y0 - 7) * W + gx];

    int t = y0 - 8;
#pragma unroll
    for (int i = 0; i < 4; ++i, t += 2)     // WARM: t = y0-8 .. y0-2
        pipe_step2<FIRST, WRITE_E, false, LE, RE, 0>(t, y0, gx, leftEdge, rightEdge, lane_ok,
                                                     in, eo, sk, OB, MB, OD, MD, acc, pf);
#pragma unroll 1
    for (int i = 0; i < 4; ++i, t += 2)     // GUARD pre: t = y0 .. y0+6
        pipe_step2<FIRST, WRITE_E, false, LE, RE, 1>(t, y0, gx, leftEdge, rightEdge, lane_ok,
                                                     in, eo, sk, OB, MB, OD, MD, acc, pf);
#pragma unroll 1
    for (int i = 0; i < 12; ++i, t += 2)    // STEADY: t = y0+8 .. y0+30
        pipe_step2<FIRST, WRITE_E, false, LE, RE, 2>(t, y0, gx, leftEdge, rightEdge, lane_ok,
                                                     in, eo, sk, OB, MB, OD, MD, acc, pf);
#pragma unroll 1
    for (int i = 0; i < 4; ++i, t += 2)     // GUARD drain: t = y0+32 .. y0+38
        pipe_step2<FIRST, WRITE_E, false, LE, RE, 1>(t, y0, gx, leftEdge, rightEdge, lane_ok,
                                                     in, eo, sk, OB, MB, OD, MD, acc, pf);
}

template<bool FIRST, bool WRITE_E, bool LE, bool RE>
__device__ __forceinline__
void sweep_edge(int y0, int gx, bool leftEdge, bool rightEdge, bool lane_ok,
                const float* __restrict__ in, float* __restrict__ eo,
                float* __restrict__ sk)
{
    float2 OB[7], MB[7], OD, MD, acc[8], pf[2];
    const float2 big2 = make_float2(BIG, BIG);
    const float2 z2   = make_float2(0.f, 0.f);
#pragma unroll
    for (int s = 0; s < 7; ++s) { OB[s] = big2; MB[s] = big2; }
    OD = big2; MD = big2;
#pragma unroll
    for (int j = 0; j < 8; ++j) acc[j] = z2;
    pf[0] = big2; pf[1] = big2;
    {
        const int r0 = y0 - 8, r1 = y0 - 7;
        if (r0 >= 0) pf[0] = *(const float2*)&in[(size_t)r0 * W + gx];
        if (r1 >= 0) pf[1] = *(const float2*)&in[(size_t)r1 * W + gx];
    }

    int t = y0 - 8;
#pragma unroll 1
    for (int i = 0; i < (RCH + 16) / 2; ++i, t += 2)
        pipe_step2<FIRST, WRITE_E, true, LE, RE, 1>(t, y0, gx, leftEdge, rightEdge, lane_ok,
                                                    in, eo, sk, OB, MB, OD, MD, acc, pf);
}

template<bool FIRST, bool WRITE_E>
__global__ __launch_bounds__(WPB * 64)
void skel_pipe(const float* __restrict__ ein, float* __restrict__ eout,
               float* __restrict__ skel)
{
    const int lane = threadIdx.x;          // 64 lanes; threadIdx.y selects the wave
    const int bx = blockIdx.x;             // band 0..8
    const int y0 = (blockIdx.y * WPB + (int)threadIdx.y) * RCH;  // private row chunk
    const int img = blockIdx.z;
    const int x0 = (bx == 0) ? 0 : ((bx == NBAND - 1) ? (W - 128) : 112 * bx);
    const int gx = x0 + 2 * lane;          // covers cols gx, gx+1; max 896+126=1022

    const size_t base = (size_t)img * (size_t)(W * H);
    const float* __restrict__ in = ein + base;
    float* __restrict__ eo = eout + base;
    float* __restrict__ sk = skel + base;

    const bool leftEdge  = (gx == 0);
    const bool rightEdge = (gx + 2 == W);
    // disjoint write ownership (bands overlap in compute, never in writes)
    const int own_lo = (bx == 0) ? 0 : 112 * bx + 8;
    const int own_hi = (bx == NBAND - 1) ? W : 112 * (bx + 1) + 8;
    const bool lane_ok = (gx >= own_lo) && (gx < own_hi);

    // interior iff 32 <= y0 <= H-RCH-32 (= 960): full warm-up cone in-image
    const bool interior = (y0 >= 32 && y0 <= H - RCH - 32);

    if (bx == 0) {
        if (interior) sweep_int <FIRST, WRITE_E, true,  false>(y0, gx, leftEdge, rightEdge, lane_ok, in, eo, sk);
        else          sweep_edge<FIRST, WRITE_E, true,  false>(y0, gx, leftEdge, rightEdge, lane_ok, in, eo, sk);
    } else if (bx == NBAND - 1) {
        if (interior) sweep_int <FIRST, WRITE_E, false, true >(y0, gx, leftEdge, rightEdge, lane_ok, in, eo, sk);
        else          sweep_edge<FIRST, WRITE_E, false, true >(y0, gx, leftEdge, rightEdge, lane_ok, in, eo, sk);
    } else {
        if (interior) sweep_int <FIRST, WRITE_E, false, false>(y0, gx, leftEdge, rightEdge, lane_ok, in, eo, sk);
        else          sweep_edge<FIRST, WRITE_E, false, false>(y0, gx, leftEdge, rightEdge, lane_ok, in, eo, sk);
    }
}

extern "C" void kernel_launch(void* const* d_in, const int* in_sizes, int n_in,
                              void* d_out, int out_size, void* d_ws, size_t ws_size,
                              hipStream_t stream)
{
    const float* x = (const float*)d_in[0];
    float* skel = (float*)d_out;
    const size_t n = (size_t)NIMG * W * H;

    float* e0 = (float*)d_ws;
    float* e1 = e0 + n;

    dim3 grid(NBAND, H / (RCH * WPB), NIMG);   // 9 x 16 x 16 = 2304 WGs = 9/CU
    dim3 block(64, WPB);

    // steps 0-6: x -> e0 ; 7-13: e0 -> e1 ; 14-20: e1 -> (none)
    skel_pipe<true,  true ><<<grid, block, 0, stream>>>(x,  e0, skel);
    skel_pipe<false, true ><<<grid, block, 0, stream>>>(e0, e1, skel);
    skel_pipe<false, false><<<grid, block, 0, stream>>>(e1, e0, skel);
}